// Round 9
// baseline (435.077 us; speedup 1.0000x reference)
//
#include <hip/hip_runtime.h>
#include <hip/hip_bf16.h>

typedef unsigned short u16;
typedef unsigned int u32;
typedef __attribute__((ext_vector_type(8))) short short8;   // 8 bf16 = 4 VGPR
typedef __attribute__((ext_vector_type(4))) float f32x4;

#define BK 32
#define LDP 40   // padded LDS row stride in u16 (80 B): breaks 8-way bank conflict, keeps 16B align

__device__ __forceinline__ float sigmoidf_(float x) { return 1.0f / (1.0f + expf(-x)); }

__device__ __forceinline__ float bf2f(u16 u) {
    union { u32 i; float f; } v; v.i = ((u32)u) << 16; return v.f;
}
__device__ __forceinline__ u16 f2bf(float f) {
    union { float f; u32 i; } v; v.f = f;
    u32 lsb = (v.i >> 16) & 1u;
    v.i += 0x7fffu + lsb;            // RNE
    return (u16)(v.i >> 16);
}

// ---------------- f32 -> bf16 weight conversion ----------------
__global__ __launch_bounds__(256) void cvt_bf16(const float* __restrict__ src,
                                                u16* __restrict__ dst, int n)
{
    int i = blockIdx.x * 256 + threadIdx.x;
    if (i < n) dst[i] = f2bf(src[i]);
}

// ---------------- leaf table: tab[sym][c], 32x512 ----------------
__global__ __launch_bounds__(256) void leaf_tab(
    const float* __restrict__ ewi, const float* __restrict__ ebi,
    const float* __restrict__ ebh, u16* __restrict__ tab)
{
    int idx = blockIdx.x * 256 + threadIdx.x;   // 32*512
    int c = idx & 511;
    int sym = idx >> 9;
    float r = sigmoidf_(ewi[c * 32 + sym]          + ebi[c]        + ebh[c]);
    float z = sigmoidf_(ewi[(512 + c) * 32 + sym]  + ebi[512 + c]  + ebh[512 + c]);
    float n = tanhf(    ewi[(1024 + c) * 32 + sym] + ebi[1024 + c] + r * ebh[1024 + c]);
    tab[idx] = f2bf((1.0f - z) * n);
}

// ---------------- Encoder leaf (d=6): gather from table ----------------
__global__ __launch_bounds__(256) void enc_leaf(
    const u16* __restrict__ tab, const int* __restrict__ symbols,
    u16* __restrict__ hout)
{
    int t = blockIdx.x * 256 + threadIdx.x;     // over 16384*64 (8 elems each)
    int m = t >> 6, c0 = (t & 63) * 8;
    int sym = symbols[(m >> 6) * 127 + 63 + (m & 63)];
    *reinterpret_cast<short8*>(hout + (size_t)m * 512 + c0) =
        *reinterpret_cast<const short8*>(tab + sym * 512 + c0);
}

// ---------------- Encoder LDS-staged MFMA GEMM + GRU (levels d=5..0) ----------------
// A: (M,1024) bf16; W: ewh bf16 (1536,1024); hout: (M,512) bf16.
// BM = RF*32 rows/block; 4 waves as 2x2; wave tile = RF*16 rows x 32 cols x 3 gates.
template<int RF>
__global__ __launch_bounds__(256, 2) void enc_tile(
    const u16* __restrict__ A, const u16* __restrict__ W,
    const float* __restrict__ ewi, const float* __restrict__ ebi,
    const float* __restrict__ ebh, const int* __restrict__ symbols,
    u16* __restrict__ hout, int dlog, int node_base)
{
    constexpr int BM = RF * 32;
    constexpr int NC = RF / 2;      // A staging chunks per thread
    __shared__ u16 Als[BM * LDP];
    __shared__ u16 Bls[192 * LDP];
    const int tid  = threadIdx.x;
    const int lane = tid & 63;
    const int wid  = tid >> 6;
    const int wr = wid >> 1, wc = wid & 1;
    const int lr = lane & 15, lk = lane >> 4;
    const int m0 = blockIdx.x * BM;
    const int c0 = blockIdx.y * 64;

    // staging chunk assignment (16B chunks)
    const int arow = tid >> 2, akp = tid & 3;
    size_t a_src[NC]; u16* a_dst[NC];
#pragma unroll
    for (int j = 0; j < NC; ++j) {
        int row = arow + j * 64;
        a_src[j] = (size_t)(m0 + row) * 1024 + akp * 8;
        a_dst[j] = Als + row * LDP + akp * 8;
    }
    size_t b_src[3]; u16* b_dst[3];
#pragma unroll
    for (int j = 0; j < 3; ++j) {
        int ch = tid + j * 256;
        int rr = ch >> 2, kp = ch & 3;
        int grow = (rr >> 6) * 512 + c0 + (rr & 63);
        b_src[j] = (size_t)grow * 1024 + kp * 8;
        b_dst[j] = Bls + rr * LDP + kp * 8;
    }

    f32x4 acc[3][2][RF];
#pragma unroll
    for (int s = 0; s < 3; ++s)
#pragma unroll
        for (int cf = 0; cf < 2; ++cf)
#pragma unroll
            for (int i = 0; i < RF; ++i) acc[s][cf][i] = (f32x4){0.f, 0.f, 0.f, 0.f};

    short8 sA[NC], sB0, sB1, sB2;
#pragma unroll
    for (int j = 0; j < NC; ++j) sA[j] = *reinterpret_cast<const short8*>(A + a_src[j]);
    sB0 = *reinterpret_cast<const short8*>(W + b_src[0]);
    sB1 = *reinterpret_cast<const short8*>(W + b_src[1]);
    sB2 = *reinterpret_cast<const short8*>(W + b_src[2]);
#pragma unroll
    for (int j = 0; j < NC; ++j) *reinterpret_cast<short8*>(a_dst[j]) = sA[j];
    *reinterpret_cast<short8*>(b_dst[0]) = sB0;
    *reinterpret_cast<short8*>(b_dst[1]) = sB1;
    *reinterpret_cast<short8*>(b_dst[2]) = sB2;
    __syncthreads();

    for (int k0 = 0;;) {
        const int nxt = k0 + BK;
        const bool more = (nxt < 1024);
        if (more) {   // early-issue next tile's global loads
#pragma unroll
            for (int j = 0; j < NC; ++j)
                sA[j] = *reinterpret_cast<const short8*>(A + a_src[j] + nxt);
            sB0 = *reinterpret_cast<const short8*>(W + b_src[0] + nxt);
            sB1 = *reinterpret_cast<const short8*>(W + b_src[1] + nxt);
            sB2 = *reinterpret_cast<const short8*>(W + b_src[2] + nxt);
        }
        short8 a[RF];
#pragma unroll
        for (int i = 0; i < RF; ++i)
            a[i] = *reinterpret_cast<const short8*>(Als + (wr * (RF * 16) + i * 16 + lr) * LDP + lk * 8);
#pragma unroll
        for (int s = 0; s < 3; ++s)
#pragma unroll
            for (int cf = 0; cf < 2; ++cf) {
                short8 b = *reinterpret_cast<const short8*>(
                    Bls + (s * 64 + wc * 32 + cf * 16 + lr) * LDP + lk * 8);
#pragma unroll
                for (int i = 0; i < RF; ++i)
                    acc[s][cf][i] = __builtin_amdgcn_mfma_f32_16x16x32_bf16(a[i], b, acc[s][cf][i], 0, 0, 0);
            }
        if (!more) break;
        __syncthreads();
#pragma unroll
        for (int j = 0; j < NC; ++j) *reinterpret_cast<short8*>(a_dst[j]) = sA[j];
        *reinterpret_cast<short8*>(b_dst[0]) = sB0;
        *reinterpret_cast<short8*>(b_dst[1]) = sB1;
        *reinterpret_cast<short8*>(b_dst[2]) = sB2;
        __syncthreads();
        k0 = nxt;
    }

    const int mask = (1 << dlog) - 1;
#pragma unroll
    for (int i = 0; i < RF; ++i)
#pragma unroll
        for (int r = 0; r < 4; ++r) {
            int m = m0 + wr * (RF * 16) + i * 16 + lk * 4 + r;
            int b_ = m >> dlog, j_ = m & mask;
            int sym = symbols[b_ * 127 + node_base + j_];
#pragma unroll
            for (int cf = 0; cf < 2; ++cf) {
                int c = c0 + wc * 32 + cf * 16 + lr;
                float rr_ = sigmoidf_(ewi[c * 32 + sym]          + ebi[c]        + acc[0][cf][i][r] + ebh[c]);
                float zz  = sigmoidf_(ewi[(512 + c) * 32 + sym]  + ebi[512 + c]  + acc[1][cf][i][r] + ebh[512 + c]);
                float nn  = tanhf(    ewi[(1024 + c) * 32 + sym] + ebi[1024 + c] + rr_ * (acc[2][cf][i][r] + ebh[1024 + c]));
                float hl = bf2f(A[(size_t)m * 1024 + c]);
                float hr = bf2f(A[(size_t)m * 1024 + 512 + c]);
                hout[(size_t)m * 512 + c] = f2bf((1.0f - zz) * nn + zz * (hl + hr) * 0.5f);
            }
        }
}

// ---------------- mid: mu/logvar/zlat ----------------
__global__ __launch_bounds__(256) void mid1(
    const u16* __restrict__ root, const float* __restrict__ h2mu_w,
    const float* __restrict__ h2mu_b, const float* __restrict__ h2lv_w,
    const float* __restrict__ h2lv_b, const float* __restrict__ eps,
    float* __restrict__ zlat, float* __restrict__ out_mu,
    float* __restrict__ out_lv)
{
    int b = blockIdx.x, t = threadIdx.x;
    __shared__ float rs[512];
    rs[t]       = bf2f(root[(size_t)b * 512 + t]);
    rs[t + 256] = bf2f(root[(size_t)b * 512 + t + 256]);
    __syncthreads();
    const float* w = (t < 128) ? (h2mu_w + (size_t)t * 512) : (h2lv_w + (size_t)(t - 128) * 512);
    float acc = 0.0f;
    for (int k = 0; k < 512; ++k) acc += rs[k] * w[k];
    acc += (t < 128) ? h2mu_b[t] : h2lv_b[t - 128];
    __shared__ float vals[256];
    vals[t] = acc;
    __syncthreads();
    if (t < 128) {
        float mu = vals[t], lv = vals[t + 128];
        float zl = mu + eps[b * 128 + t] * expf(0.5f * lv);
        zlat[b * 128 + t] = zl;
        out_mu[b * 128 + t] = mu;
        out_lv[b * 128 + t] = lv;
    }
}

__global__ __launch_bounds__(512) void mid2(
    const float* __restrict__ zlat, const float* __restrict__ z2h_w,
    const float* __restrict__ z2h_b, u16* __restrict__ hidden)
{
    int b = blockIdx.x, t = threadIdx.x;
    __shared__ float zs[128];
    if (t < 128) zs[t] = zlat[b * 128 + t];
    __syncthreads();
    float acc = z2h_b[t];
    for (int k = 0; k < 128; ++k) acc += zs[k] * z2h_w[(size_t)t * 128 + k];
    hidden[(size_t)b * 512 + t] = f2bf(acc);
}

// ---------------- decoder pred via MFMA + in-register softmax ----------------
__global__ __launch_bounds__(256) void pred_mfma(
    const u16* __restrict__ hidden, const u16* __restrict__ Wo,
    const float* __restrict__ h2o_b, u16* __restrict__ aout,
    float* __restrict__ preds_out, int dlog, int node_base, int write_a)
{
    const int lane = threadIdx.x & 63;
    const int wid  = threadIdx.x >> 6;
    const int lr = lane & 15, lk = lane >> 4;
    const int m0 = blockIdx.x * 64 + wid * 16;

    f32x4 acc0 = (f32x4){0.f, 0.f, 0.f, 0.f};
    f32x4 acc1 = (f32x4){0.f, 0.f, 0.f, 0.f};
    const u16* Arow = hidden + (size_t)(m0 + lr) * 512 + lk * 8;
    const u16* B0 = Wo + (size_t)lr * 512 + lk * 8;
    const u16* B1 = Wo + (size_t)(16 + lr) * 512 + lk * 8;
#pragma unroll
    for (int k0 = 0; k0 < 512; k0 += 32) {
        short8 a  = *reinterpret_cast<const short8*>(Arow + k0);
        short8 b0 = *reinterpret_cast<const short8*>(B0 + k0);
        short8 b1 = *reinterpret_cast<const short8*>(B1 + k0);
        acc0 = __builtin_amdgcn_mfma_f32_16x16x32_bf16(a, b0, acc0, 0, 0, 0);
        acc1 = __builtin_amdgcn_mfma_f32_16x16x32_bf16(a, b1, acc1, 0, 0, 0);
    }
    const float bb0 = h2o_b[lr], bb1 = h2o_b[16 + lr];
    const int dmask = (1 << dlog) - 1;
#pragma unroll
    for (int r = 0; r < 4; ++r) {
        float p0 = acc0[r] + bb0;
        float p1 = acc1[r] + bb1;
        float mx = fmaxf(p0, p1);
#pragma unroll
        for (int off = 1; off < 16; off <<= 1) mx = fmaxf(mx, __shfl_xor(mx, off));
        float e0 = expf(p0 - mx), e1 = expf(p1 - mx);
        float s = e0 + e1;
#pragma unroll
        for (int off = 1; off < 16; off <<= 1) s += __shfl_xor(s, off);
        int m = m0 + lk * 4 + r;
        int b_ = m >> dlog, j_ = m & dmask;
        size_t o = (size_t)(b_ * 127 + node_base + j_) * 32;
        preds_out[o + lr] = p0;
        preds_out[o + 16 + lr] = p1;
        if (write_a) {
            float inv = 1.0f / s;
            aout[(size_t)m * 32 + lr]      = f2bf(e0 * inv);
            aout[(size_t)m * 32 + 16 + lr] = f2bf(e1 * inv);
        }
    }
}

// ---------------- decoder LDS-staged MFMA GRU (levels d=0..5) ----------------
template<int RF>
__global__ __launch_bounds__(256, 2) void dec_tile(
    const u16* __restrict__ Hin, const u16* __restrict__ aB,
    const u16* __restrict__ Wh, const u16* __restrict__ Wi,
    const float* __restrict__ dbh, const float* __restrict__ dbi,
    u16* __restrict__ Hout)
{
    constexpr int BM = RF * 32;
    constexpr int NC = RF / 2;
    __shared__ u16 Als[BM * LDP];
    __shared__ u16 Bls[192 * LDP];
    const int tid  = threadIdx.x;
    const int lane = tid & 63;
    const int wid  = tid >> 6;
    const int wr = wid >> 1, wc = wid & 1;
    const int lr = lane & 15, lk = lane >> 4;
    const int m0 = blockIdx.x * BM;
    const int c0 = blockIdx.y * 64;      // within 1024

    const int arow = tid >> 2, akp = tid & 3;
    size_t a_src[NC]; u16* a_dst[NC];
#pragma unroll
    for (int j = 0; j < NC; ++j) {
        int row = arow + j * 64;
        a_src[j] = (size_t)(m0 + row) * 512 + akp * 8;
        a_dst[j] = Als + row * LDP + akp * 8;
    }
    size_t b_src[3]; u16* b_dst[3];
#pragma unroll
    for (int j = 0; j < 3; ++j) {
        int ch = tid + j * 256;
        int rr = ch >> 2, kp = ch & 3;
        int grow = (rr >> 6) * 1024 + c0 + (rr & 63);
        b_src[j] = (size_t)grow * 512 + kp * 8;
        b_dst[j] = Bls + rr * LDP + kp * 8;
    }

    f32x4 acc[4][2][RF];
#pragma unroll
    for (int s = 0; s < 4; ++s)
#pragma unroll
        for (int cf = 0; cf < 2; ++cf)
#pragma unroll
            for (int i = 0; i < RF; ++i) acc[s][cf][i] = (f32x4){0.f, 0.f, 0.f, 0.f};

    short8 sA[NC], sB0, sB1, sB2;
#pragma unroll
    for (int j = 0; j < NC; ++j) sA[j] = *reinterpret_cast<const short8*>(Hin + a_src[j]);
    sB0 = *reinterpret_cast<const short8*>(Wh + b_src[0]);
    sB1 = *reinterpret_cast<const short8*>(Wh + b_src[1]);
    sB2 = *reinterpret_cast<const short8*>(Wh + b_src[2]);
#pragma unroll
    for (int j = 0; j < NC; ++j) *reinterpret_cast<short8*>(a_dst[j]) = sA[j];
    *reinterpret_cast<short8*>(b_dst[0]) = sB0;
    *reinterpret_cast<short8*>(b_dst[1]) = sB1;
    *reinterpret_cast<short8*>(b_dst[2]) = sB2;
    __syncthreads();

    for (int k0 = 0;;) {
        const int nxt = k0 + BK;
        const bool more = (nxt < 512);
        if (more) {
#pragma unroll
            for (int j = 0; j < NC; ++j)
                sA[j] = *reinterpret_cast<const short8*>(Hin + a_src[j] + nxt);
            sB0 = *reinterpret_cast<const short8*>(Wh + b_src[0] + nxt);
            sB1 = *reinterpret_cast<const short8*>(Wh + b_src[1] + nxt);
            sB2 = *reinterpret_cast<const short8*>(Wh + b_src[2] + nxt);
        }
        short8 a[RF];
#pragma unroll
        for (int i = 0; i < RF; ++i)
            a[i] = *reinterpret_cast<const short8*>(Als + (wr * (RF * 16) + i * 16 + lr) * LDP + lk * 8);
#pragma unroll
        for (int s = 0; s < 3; ++s)
#pragma unroll
            for (int cf = 0; cf < 2; ++cf) {
                short8 b = *reinterpret_cast<const short8*>(
                    Bls + (s * 64 + wc * 32 + cf * 16 + lr) * LDP + lk * 8);
#pragma unroll
                for (int i = 0; i < RF; ++i)
                    acc[s][cf][i] = __builtin_amdgcn_mfma_f32_16x16x32_bf16(a[i], b, acc[s][cf][i], 0, 0, 0);
            }
        if (!more) break;
        __syncthreads();
#pragma unroll
        for (int j = 0; j < NC; ++j) *reinterpret_cast<short8*>(a_dst[j]) = sA[j];
        *reinterpret_cast<short8*>(b_dst[0]) = sB0;
        *reinterpret_cast<short8*>(b_dst[1]) = sB1;
        *reinterpret_cast<short8*>(b_dst[2]) = sB2;
        __syncthreads();
        k0 = nxt;
    }

    // rank-32 input-gate contribution straight from global (small)
    {
#pragma unroll
        for (int i = 0; i < RF; ++i) {
            short8 aw = *reinterpret_cast<const short8*>(
                aB + (size_t)(m0 + wr * (RF * 16) + i * 16 + lr) * 32 + lk * 8);
#pragma unroll
            for (int s = 0; s < 3; ++s) {
                const int d = (s == 2) ? 3 : s;
#pragma unroll
                for (int cf = 0; cf < 2; ++cf) {
                    short8 b = *reinterpret_cast<const short8*>(
                        Wi + (size_t)(s * 1024 + c0 + wc * 32 + cf * 16 + lr) * 32 + lk * 8);
                    acc[d][cf][i] = __builtin_amdgcn_mfma_f32_16x16x32_bf16(aw, b, acc[d][cf][i], 0, 0, 0);
                }
            }
        }
    }

#pragma unroll
    for (int i = 0; i < RF; ++i)
#pragma unroll
        for (int r = 0; r < 4; ++r) {
            int m = m0 + wr * (RF * 16) + i * 16 + lk * 4 + r;
#pragma unroll
            for (int cf = 0; cf < 2; ++cf) {
                int c = c0 + wc * 32 + cf * 16 + lr;
                float rr_ = sigmoidf_(acc[0][cf][i][r] + dbh[c]        + dbi[c]);
                float zz  = sigmoidf_(acc[1][cf][i][r] + dbh[1024 + c] + dbi[1024 + c]);
                float nn  = tanhf(acc[3][cf][i][r] + dbi[2048 + c] + rr_ * (acc[2][cf][i][r] + dbh[2048 + c]));
                float hid = bf2f(Hin[(size_t)m * 512 + (c & 511)]);
                Hout[(size_t)m * 1024 + c] = f2bf((1.0f - zz) * nn + zz * hid);
            }
        }
}

extern "C" void kernel_launch(void* const* d_in, const int* in_sizes, int n_in,
                              void* d_out, int out_size, void* d_ws, size_t ws_size,
                              hipStream_t stream) {
    const int*   symbols = (const int*)  d_in[0];
    const float* eps     = (const float*)d_in[1];
    const float* ewi     = (const float*)d_in[2];
    const float* ebi     = (const float*)d_in[3];
    const float* ewh     = (const float*)d_in[4];
    const float* ebh     = (const float*)d_in[5];
    const float* h2mu_w  = (const float*)d_in[6];
    const float* h2mu_b  = (const float*)d_in[7];
    const float* h2lv_w  = (const float*)d_in[8];
    const float* h2lv_b  = (const float*)d_in[9];
    const float* z2h_w   = (const float*)d_in[10];
    const float* z2h_b   = (const float*)d_in[11];
    const float* h2o_w   = (const float*)d_in[12];
    const float* h2o_b   = (const float*)d_in[13];
    const float* dwi     = (const float*)d_in[14];
    const float* dbi     = (const float*)d_in[15];
    const float* dwh     = (const float*)d_in[16];
    const float* dbh     = (const float*)d_in[17];

    float* out    = (float*)d_out;
    float* out_mu = out;
    float* out_lv = out + 256 * 128;
    float* out_pr = out + 2 * 256 * 128;

    // ---- workspace layout (~32.4 MB) ----
    u16* bufL  = (u16*)d_ws;                            // 16384*512
    u16* bufS  = bufL  + (size_t)16384 * 512;           //  8192*512
    u16* ewh_b = bufS  + (size_t)8192 * 512;            // 1536*1024
    u16* dwh_b = ewh_b + (size_t)1536 * 1024;           // 3072*512
    u16* dwi_b = dwh_b + (size_t)3072 * 512;            // 3072*32
    u16* wo_b  = dwi_b + (size_t)3072 * 32;             // 32*512
    u16* ltab  = wo_b  + (size_t)32 * 512;              // 32*512
    u16* aBuf  = ltab  + (size_t)32 * 512;              // 8192*32
    float* zlat = (float*)(aBuf + (size_t)8192 * 32);   // 256*128 f32

    // ---- weight conversion + leaf table (once per call) ----
    cvt_bf16<<<(1572864 + 255) / 256, 256, 0, stream>>>(ewh, ewh_b, 1572864);
    cvt_bf16<<<(1572864 + 255) / 256, 256, 0, stream>>>(dwh, dwh_b, 1572864);
    cvt_bf16<<<(98304 + 255) / 256, 256, 0, stream>>>(dwi, dwi_b, 98304);
    cvt_bf16<<<(16384 + 255) / 256, 256, 0, stream>>>(h2o_w, wo_b, 16384);
    leaf_tab<<<64, 256, 0, stream>>>(ewi, ebi, ebh, ltab);

    // ---- encoder ----
    enc_leaf<<<4096, 256, 0, stream>>>(ltab, symbols, bufL);
    const u16* src = bufL;
    u16*       dst = bufS;
    for (int d = 5; d >= 0; --d) {
        int M = 256 << d;
        if (M >= 4096)
            enc_tile<4><<<dim3(M / 128, 8), 256, 0, stream>>>(src, ewh_b, ewi, ebi, ebh, symbols,
                                                              dst, d, (1 << d) - 1);
        else
            enc_tile<2><<<dim3(M / 64, 8), 256, 0, stream>>>(src, ewh_b, ewi, ebi, ebh, symbols,
                                                             dst, d, (1 << d) - 1);
        const u16* t = src; src = dst; dst = (u16*)t;
    }
    // root in bufL
    mid1<<<256, 256, 0, stream>>>(src, h2mu_w, h2mu_b, h2lv_w, h2lv_b, eps, zlat, out_mu, out_lv);
    mid2<<<256, 512, 0, stream>>>(zlat, z2h_w, z2h_b, bufL);   // hidden0 -> bufL

    // ---- decoder ---- parity: d4 fills bufS exactly, d5 fills bufL exactly
    const u16* hsrc = bufL;
    u16*       hdst = bufS;
    for (int d = 0; d < 6; ++d) {
        int M = 256 << d;
        pred_mfma<<<M / 64, 256, 0, stream>>>(hsrc, wo_b, h2o_b, aBuf, out_pr, d, (1 << d) - 1, 1);
        if (M >= 4096)
            dec_tile<4><<<dim3(M / 128, 16), 256, 0, stream>>>(hsrc, aBuf, dwh_b, dwi_b, dbh, dbi, hdst);
        else
            dec_tile<2><<<dim3(M / 64, 16), 256, 0, stream>>>(hsrc, aBuf, dwh_b, dwi_b, dbh, dbi, hdst);
        const u16* t = hsrc; hsrc = hdst; hdst = (u16*)t;
    }
    pred_mfma<<<16384 / 64, 256, 0, stream>>>(hsrc, wo_b, h2o_b, aBuf, out_pr, 6, 63, 0);
}